// Round 7
// baseline (231.320 us; speedup 1.0000x reference)
//
#include <hip/hip_runtime.h>
#include <hip/hip_bf16.h>

typedef unsigned short u16;
typedef unsigned int u32;
typedef short bf16x8 __attribute__((ext_vector_type(8)));
typedef float f32x4 __attribute__((ext_vector_type(4)));
typedef u16 u16x8 __attribute__((ext_vector_type(8)));

#define HID 1024
#define BATCH 4096
#define KTOT 2048   // concat K: [x | h_prev]
// Fragment-linear layouts: unit u = tile16*64 + kstep (kstep = k/32), 1KB per
// unit; within a unit, lane l = quad*16 + m holds elems [m][quad*8 .. +8)
// (the exact 16x16x32 A/B fragment). GEMM loads these with coalesced dwordx4.

__device__ __forceinline__ u16 f2bf(float f) {
  u32 v = __builtin_bit_cast(u32, f);
  u32 r = (v + 0x7fffu + ((v >> 16) & 1u)) >> 16;  // round-nearest-even
  return (u16)r;
}
__device__ __forceinline__ float sigmoid_fast(float x) {
  return 1.0f / (1.0f + __expf(-x));
}
__device__ __forceinline__ float tanh_fast(float x) {
  return 2.0f * sigmoid_fast(2.0f * x) - 1.0f;
}

// ---------------------------------------------------------------------------
// prep_xh: xh2 in A-fragment-linear layout from f32 x|h_prev.
// slot s = global thread id; unit = s>>6 (rowtile = unit>>6, kstep = unit&63),
// lane = s&63 (m = lane&15, quad = lane>>4). Writes 16B/lane fully coalesced.
// ---------------------------------------------------------------------------
__global__ __launch_bounds__(256) void prep_xh(
    const float* __restrict__ x, const float* __restrict__ hp,
    u16* __restrict__ xh2) {
  int s = blockIdx.x * 256 + threadIdx.x;
  int lane = s & 63, unit = s >> 6;
  int kstep = unit & 63, rowtile = unit >> 6;
  int m = lane & 15, quad = lane >> 4;
  int row = rowtile * 16 + m;
  int kg = kstep * 32 + quad * 8;
  const float* src = (kg < 1024) ? (x + (size_t)row * 1024 + kg)
                                 : (hp + (size_t)row * 1024 + (kg - 1024));
  f32x4 a = *(const f32x4*)(src);
  f32x4 b = *(const f32x4*)(src + 4);
  u16x8 v;
#pragma unroll
  for (int j = 0; j < 4; ++j) { v[j] = f2bf(a[j]); v[j + 4] = f2bf(b[j]); }
  *(u16x8*)(xh2 + (size_t)s * 8) = v;
}

// ---------------------------------------------------------------------------
// prep_w: f32 weights -> bt in B-fragment-linear layout, gate-interleaved:
//   n' = (h/16)*64 + g*16 + (h%16); ntile = (h>>4)*4 + g (4 consecutive
//   ntiles of a superblock = gates i,f,o,c of the same 16 hidden cols).
// Stage 1: coalesced reads -> bf16 -> LDS (row stride 66 u16 rotation).
// Stage 2: each 32-thread group fills one complete 1KB fragment unit with
//          fully-coalesced contiguous writes (32 x 32B). LDS gather aliasing
//          is <=2-way (free).
// ---------------------------------------------------------------------------
__global__ __launch_bounds__(256) void prep_w(
    const float* __restrict__ igx, const float* __restrict__ fgx,
    const float* __restrict__ ogx, const float* __restrict__ cgx,
    const float* __restrict__ igu, const float* __restrict__ fgu,
    const float* __restrict__ ogu, const float* __restrict__ cgu,
    u16* __restrict__ bt) {
  __shared__ u16 lds[64 * 66];
  const float* srcs[8] = {igx, fgx, ogx, cgx, igu, fgu, ogu, cgu};
  int bid = blockIdx.x;
  int m = bid >> 8;            // matrix 0..7
  int tile = bid & 255;        // 64x64 tile
  int th = tile & 15, tk = tile >> 4;
  int h0 = th << 6, k0 = tk << 6;
  int g = m & 3, which = m >> 2;
  const float* W = srcs[m] + (size_t)k0 * HID + h0;

  int t = threadIdx.x;

  // stage 1: rows k0..k0+63, cols h0..h0+63 -> LDS[k][h]
  int r1 = t >> 4;             // 0..15 (row within pass)
  int c1 = (t & 15) << 2;      // 0,4,..,60
#pragma unroll
  for (int p = 0; p < 4; ++p) {
    int row = (p << 4) + r1;
    f32x4 v = *(const f32x4*)(W + (size_t)row * HID + c1);
    u32 p0 = (u32)f2bf(v[0]) | ((u32)f2bf(v[1]) << 16);
    u32 p1 = (u32)f2bf(v[2]) | ((u32)f2bf(v[3]) << 16);
    u32* d = (u32*)&lds[row * 66 + c1];
    d[0] = p0;
    d[1] = p1;
  }
  __syncthreads();

  // stage 2: 8 units per block (4 ntiles x 2 ksteps); 32 threads per unit,
  // thread writes fragment slots s0 = 2*(t&31) and s0+1 (32B contiguous).
  int u = t >> 5;              // 0..7
  int j = u & 3, ks = u >> 2;  // ntile sel, kstep sel
  int s0 = (t & 31) << 1;
  int ntile = (((h0 >> 4) + j) << 2) | g;
  size_t unit = (size_t)ntile * 64 + (size_t)which * 32 + (k0 >> 5) + ks;
  u16* dst = bt + unit * 512 + (size_t)s0 * 8;
#pragma unroll
  for (int p = 0; p < 2; ++p) {
    int s = s0 + p;
    int m16 = s & 15, quad = s >> 4;
    u16x8 v;
#pragma unroll
    for (int jj = 0; jj < 8; ++jj)
      v[jj] = lds[(ks * 32 + quad * 8 + jj) * 66 + (j << 4) + m16];
    *(u16x8*)(dst + p * 8) = v;
  }
}

// ---------------------------------------------------------------------------
// lstm_gemm: fragment-direct, zero LDS / zero barriers. ONE WAVE per block,
// 64x64 wave tile, grid 4096 XCD-swizzled (each XCD's L2 keeps a 2MB bt
// slice hot). Register double-buffer with sched_group_barrier pins (8 VMEM
// reads then 16 MFMAs per half) so the scheduler cannot collapse the
// software pipeline. Fused LSTM epilogue (f32 in/out); wave's 4 n-tiles =
// gates i,f,o,c of the same 16 hidden cols.
// ---------------------------------------------------------------------------
#define LOAD_FRAGS(buf, kstep_)                                              \
  {                                                                          \
    int _kk = (kstep_);                                                      \
    af[buf][0]  = *(const bf16x8*)(pA + (size_t)(0 * 64 + _kk) * 512);       \
    bfr[buf][0] = *(const bf16x8*)(pB + (size_t)(0 * 64 + _kk) * 512);       \
    bfr[buf][1] = *(const bf16x8*)(pB + (size_t)(1 * 64 + _kk) * 512);       \
    bfr[buf][2] = *(const bf16x8*)(pB + (size_t)(2 * 64 + _kk) * 512);       \
    bfr[buf][3] = *(const bf16x8*)(pB + (size_t)(3 * 64 + _kk) * 512);       \
    af[buf][1]  = *(const bf16x8*)(pA + (size_t)(1 * 64 + _kk) * 512);       \
    af[buf][2]  = *(const bf16x8*)(pA + (size_t)(2 * 64 + _kk) * 512);       \
    af[buf][3]  = *(const bf16x8*)(pA + (size_t)(3 * 64 + _kk) * 512);       \
  }

#define CONSUME_FRAGS(buf)                                                   \
  {                                                                          \
    _Pragma("unroll") for (int mi = 0; mi < 4; ++mi)                         \
        _Pragma("unroll") for (int ni = 0; ni < 4; ++ni)                     \
            acc[mi][ni] = __builtin_amdgcn_mfma_f32_16x16x32_bf16(           \
                af[buf][mi], bfr[buf][ni], acc[mi][ni], 0, 0, 0);            \
  }

#define SCHED_PIN()                                                          \
  __builtin_amdgcn_sched_group_barrier(0x020, 8, 0);  /* 8 VMEM reads */     \
  __builtin_amdgcn_sched_group_barrier(0x008, 16, 0); /* 16 MFMAs */

__global__ __launch_bounds__(64) void lstm_gemm(
    const u16* __restrict__ xh2, const u16* __restrict__ bt,
    const float* __restrict__ cprev,
    const float* __restrict__ ib, const float* __restrict__ fb,
    const float* __restrict__ ob, const float* __restrict__ cb,
    float* __restrict__ hout, float* __restrict__ cout) {
  int l = threadIdx.x;
  int bid = blockIdx.x;
  // XCD swizzle: consecutive bids round-robin XCDs; give XCD k bcols
  // [8k, 8k+8) so its 2MB bt slice stays L2-resident.
  int bcol = ((bid & 7) << 3) | ((bid >> 3) & 7);
  int brow = bid >> 6;
  int lrow = l & 15, quad = l >> 4;

  f32x4 acc[4][4] = {};
  bf16x8 af[2][4], bfr[2][4];

  const u16* pA = xh2 + ((size_t)(brow * 4) * 64) * 512 + l * 8;
  const u16* pB = bt  + ((size_t)(bcol * 4) * 64) * 512 + l * 8;

  LOAD_FRAGS(0, 0)
  for (int kt = 0; kt < 64; kt += 2) {
    LOAD_FRAGS(1, kt + 1)
    CONSUME_FRAGS(0)
    SCHED_PIN()
    LOAD_FRAGS(0, (kt + 2) & 63)   // kt=62 wraps to 0: valid mem, unused
    CONSUME_FRAGS(1)
    SCHED_PIN()
  }

  // Epilogue: n-tiles ni = gates i,f,o,c for hidden cols hcol.
  int hcol = bcol * 16 + lrow;
  float bi = ib[hcol];
  float bff = fb[hcol];
  float bo = ob[hcol];
  float bc = cb[hcol];
  int grow = brow * 64;

#pragma unroll
  for (int mi = 0; mi < 4; ++mi) {
    int row0 = grow + mi * 16 + quad * 4;
#pragma unroll
    for (int r = 0; r < 4; ++r) {
      size_t idx = (size_t)(row0 + r) * HID + hcol;
      float gi = sigmoid_fast(acc[mi][0][r] + bi);
      float gf = sigmoid_fast(acc[mi][1][r] + bff);
      float go = sigmoid_fast(acc[mi][2][r] + bo);
      float gc = tanh_fast(acc[mi][3][r] + bc);
      float cp = cprev[idx];
      float cv = gf * cp + gi * gc;
      float hv = go * tanh_fast(cv);
      hout[idx] = hv;
      cout[idx] = cv;
    }
  }
}

extern "C" void kernel_launch(void* const* d_in, const int* in_sizes, int n_in,
                              void* d_out, int out_size, void* d_ws, size_t ws_size,
                              hipStream_t stream) {
  const float* x   = (const float*)d_in[0];
  const float* hp  = (const float*)d_in[1];
  const float* cp  = (const float*)d_in[2];
  const float* igx = (const float*)d_in[3];
  const float* igu = (const float*)d_in[4];
  const float* ib  = (const float*)d_in[5];
  const float* fgx = (const float*)d_in[6];
  const float* fgu = (const float*)d_in[7];
  const float* fb  = (const float*)d_in[8];
  const float* ogx = (const float*)d_in[9];
  const float* ogu = (const float*)d_in[10];
  const float* ob  = (const float*)d_in[11];
  const float* cgx = (const float*)d_in[12];
  const float* cgu = (const float*)d_in[13];
  const float* cb  = (const float*)d_in[14];

  u16* bt  = (u16*)d_ws;                        // B frags: 16 MiB
  u16* xh2 = bt + (size_t)4096 * 2048;          // A frags: 16 MiB
  float* hout = (float*)d_out;
  float* cout = hout + (size_t)BATCH * HID;

  prep_xh<<<4096, 256, 0, stream>>>(x, hp, xh2);
  prep_w<<<2048, 256, 0, stream>>>(igx, fgx, ogx, cgx, igu, fgu, ogu, cgu, bt);
  lstm_gemm<<<4096, 64, 0, stream>>>(xh2, bt, cp, ib, fb, ob, cb, hout, cout);
}